// Round 11
// baseline (397.842 us; speedup 1.0000x reference)
//
#include <hip/hip_runtime.h>
#include <hip/hip_bf16.h>

// Problem constants: B=4, T=2048, C=1024, NH=16, HD=64
#define TSEQ   2048
#define CDIM   1024
#define NHEAD  16
#define HDIM   64

typedef float f32x4  __attribute__((ext_vector_type(4)));
typedef float f32x16v __attribute__((ext_vector_type(16)));
typedef __bf16 bf16x8 __attribute__((ext_vector_type(8)));
typedef unsigned short u16x8 __attribute__((ext_vector_type(8)));
typedef unsigned short u16x4 __attribute__((ext_vector_type(4)));
typedef unsigned int   u32x4 __attribute__((ext_vector_type(4)));

#define QSCALE 0.18033688011112042f   // 0.125 * log2(e)
#define LOG2E  1.4426950408889634f

static __device__ __forceinline__ unsigned short f2bf(float f) {
    unsigned u = __builtin_bit_cast(unsigned, f);
    unsigned r = u + 0x7FFFu + ((u >> 16) & 1u);   // round-to-nearest-even
    return (unsigned short)(r >> 16);
}
static __device__ __forceinline__ float bf2f(unsigned short u) {
    unsigned v = ((unsigned)u) << 16;
    return __builtin_bit_cast(float, v);
}

static __device__ __forceinline__ f32x4 mfma16(u16x8 a, u16x8 b, f32x4 c) {
    return __builtin_amdgcn_mfma_f32_16x16x32_bf16(
        __builtin_bit_cast(bf16x8, a), __builtin_bit_cast(bf16x8, b), c, 0, 0, 0);
}
static __device__ __forceinline__ f32x16v mfma32(u16x8 a, u16x8 b, f32x16v c) {
    return __builtin_amdgcn_mfma_f32_32x32x16_bf16(
        __builtin_bit_cast(bf16x8, a), __builtin_bit_cast(bf16x8, b), c, 0, 0, 0);
}

static __device__ __forceinline__ void gload16(const void* g, void* l) {
    __builtin_amdgcn_global_load_lds(
        (const __attribute__((address_space(1))) unsigned int*)g,
        (__attribute__((address_space(3))) unsigned int*)l, 16, 0, 0);
}

// Workspace layout (u16 units):
//   wb   : 0        .. 4194303   (W^T q,k,v,o bf16, 1M each -- TRANSPOSED [n][k])
//   xb   : 4194304  .. 12582911  (x bf16, 8M) -- reused as `ao` after QKV GEMM
//   qh   : 12582912 .. 20971519  ([B,NH,T,HD] bf16, pre-scaled by QSCALE)
//   kh   : 20971520 .. 29359103  ([B,NH,T,HD] bf16)
//   vt   : 29359104 .. 37748735  ([B,NH,HD,T] bf16 -- V TRANSPOSED)
//   part : 37748736 .. 40894463  (384 slots x 128x64 bf16 O-partials)
//   mlb  : 40894464 .. 41091071  (384 x 128 x 2 f32 (m,l))   -- total 82.2 MB

// ---------------------------------------------------------------------------
__global__ __launch_bounds__(256) void castx(
    const float* __restrict__ x, unsigned short* __restrict__ xb)
{
    int t = blockIdx.x * 256 + threadIdx.x;   // float4 index, < 2097152
    f32x4 v = *(const f32x4*)&x[t * 4];
    u16x4 o;
    o[0] = f2bf(v[0]); o[1] = f2bf(v[1]); o[2] = f2bf(v[2]); o[3] = f2bf(v[3]);
    *(u16x4*)&xb[t * 4] = o;
}

// ---------------------------------------------------------------------------
__global__ __launch_bounds__(256) void wtcast(
    const float* __restrict__ wq, const float* __restrict__ wk,
    const float* __restrict__ wv, const float* __restrict__ wo,
    unsigned short* __restrict__ wt)
{
    __shared__ unsigned short t[64 * 72];
    const int z = blockIdx.z;
    const float* src = (z == 0) ? wq : (z == 1) ? wk : (z == 2) ? wv : wo;
    const int k0 = blockIdx.x * 64, n0 = blockIdx.y * 64, tid = threadIdx.x;

    #pragma unroll
    for (int i = 0; i < 4; ++i) {
        int idx = i * 256 + tid;
        int r = idx >> 4, c4 = idx & 15;
        f32x4 v = *(const f32x4*)&src[(k0 + r) * 1024 + n0 + c4 * 4];
        u16x4 o;
        o[0] = f2bf(v[0]); o[1] = f2bf(v[1]); o[2] = f2bf(v[2]); o[3] = f2bf(v[3]);
        *(u16x4*)&t[r * 72 + c4 * 4] = o;
    }
    __syncthreads();
    #pragma unroll
    for (int i = 0; i < 2; ++i) {
        int idx = i * 256 + tid;
        int n = idx >> 3, k8 = idx & 7;
        u16x8 o;
        #pragma unroll
        for (int e = 0; e < 8; ++e) o[e] = t[(k8 * 8 + e) * 72 + n];
        *(u16x8*)&wt[z * 1048576 + (n0 + n) * 1024 + k0 + k8 * 8] = o;
    }
}

// ---------------------------------------------------------------------------
template<int MODE>
__global__ __launch_bounds__(256) void gemm_gl(
    const unsigned short* __restrict__ A, const unsigned short* __restrict__ WT,
    unsigned short* __restrict__ outb, float* __restrict__ outf)
{
    __shared__ __align__(16) unsigned short Al[128 * 64];
    __shared__ __align__(16) unsigned short Bl[128 * 64];

    const int tid  = threadIdx.x;
    const int z    = blockIdx.z;
    const int m0   = blockIdx.y * 128;
    const int n0   = blockIdx.x * 128;
    const unsigned short* W = WT + (MODE == 0 ? z * 1048576 : 0);

    const int wid  = tid >> 6, lane = tid & 63;
    const int wr   = (wid >> 1) * 64, wc = (wid & 1) * 64;
    const int lrow = lane & 15, lk = (lane >> 4) * 8;

    f32x4 acc[4][4] = {};

    for (int kt = 0; kt < 16; ++kt) {
        __syncthreads();
        #pragma unroll
        for (int c = 0; c < 4; ++c) {
            int cz = wid * 4 + c;
            int row = cz * 8 + (lane >> 3), col = (lane & 7) * 8;
            gload16(&A[(m0 + row) * 1024 + kt * 64 + col], &Al[cz * 512]);
            gload16(&W[(n0 + row) * 1024 + kt * 64 + col], &Bl[cz * 512]);
        }
        __syncthreads();
        #pragma unroll
        for (int ks = 0; ks < 2; ++ks) {
            u16x8 af[4], bfr[4];
            #pragma unroll
            for (int m = 0; m < 4; ++m)
                af[m] = *(const u16x8*)&Al[(wr + m * 16 + lrow) * 64 + ks * 32 + lk];
            #pragma unroll
            for (int n = 0; n < 4; ++n)
                bfr[n] = *(const u16x8*)&Bl[(wc + n * 16 + lrow) * 64 + ks * 32 + lk];
            #pragma unroll
            for (int m = 0; m < 4; ++m)
                #pragma unroll
                for (int n = 0; n < 4; ++n)
                    acc[m][n] = mfma16(af[m], bfr[n], acc[m][n]);
        }
    }

    const int g = lane >> 4;
    #pragma unroll
    for (int m = 0; m < 4; ++m)
        #pragma unroll
        for (int n = 0; n < 4; ++n)
            #pragma unroll
            for (int j = 0; j < 4; ++j) {
                int grow = m0 + wr + m * 16 + g * 4 + j;
                int gcol = n0 + wc + n * 16 + lrow;
                float val = acc[m][n][j];
                if (MODE == 0) {
                    int b = grow >> 11, t = grow & 2047;
                    int h = gcol >> 6,  d = gcol & 63;
                    if (z == 0) val *= QSCALE;
                    if (z == 2)
                        outb[z * 8388608 + (((b << 4) + h) * 64 + d) * 2048 + t] = f2bf(val);
                    else
                        outb[z * 8388608 + (((b << 4) + h) * 2048 + t) * 64 + d] = f2bf(val);
                } else {
                    outf[grow * 1024 + gcol] = val;
                }
            }
}

// ---------------------------------------------------------------------------
// Kernel 3: split-KV flash attention. KVBLK=128, r6-proven body (XOR-swizzled
// global_load_lds staging, swapped QK^T 32x32, one barrier/tile) + ALiBi
// window + diag-frag skip + raw-max bound + defer-max.
// Task (bh, c): windowed tile range [t0, c], n tiles. n > 9 -> split into two
// segments (<= 8 tiles each); each segment writes unnormalized bf16 O-partial
// + (m,l); combine2 merges. Unsplit tasks write ao directly.
// Grid (32 = c x seg heavy-first, 64 b*h). 256 thr = 4 waves x 32 q-rows.
// ---------------------------------------------------------------------------
__global__ __launch_bounds__(256) void attn128s(
    const unsigned short* __restrict__ qh, const unsigned short* __restrict__ kh,
    const unsigned short* __restrict__ vt, unsigned short* __restrict__ part,
    float* __restrict__ mlb, unsigned short* __restrict__ aout)
{
    __shared__ __align__(16) unsigned short Kl[2][128 * 64];
    __shared__ __align__(16) unsigned short Vl[2][64 * 128];

    const int xx  = blockIdx.x;            // 0..31
    const int c   = 15 - (xx >> 1);        // heavy q-chunks first
    const int seg = xx & 1;
    const int bh  = blockIdx.y;
    const int h   = bh & 15, b = bh >> 4;

    const float slope2 = exp2f(-0.5f * (float)(h + 1)) * LOG2E;
    const int   Wwin   = (int)ceilf(40.0f / slope2);

    int t0i = c * 128 - Wwin;
    const int t0 = (t0i > 0) ? (t0i >> 7) : 0;
    const int n  = c - t0 + 1;
    const bool split = (n > 9);            // implies h >= 10, c >= 9
    if (!split && seg) return;

    int tlo, thi;
    if (split) {
        int h1 = (n + 1) >> 1;             // seg0 length (<= 8)
        tlo = seg ? (t0 + h1) : t0;
        thi = seg ? c : (t0 + h1 - 1);
    } else { tlo = t0; thi = c; }

    const int tid = threadIdx.x, wid = tid >> 6, lane = tid & 63;
    const int l31 = lane & 31, hi = lane >> 5;
    const int qw = c * 128 + wid * 32;
    const int qg = qw + l31;

    const unsigned short* Qb = qh + bh * (TSEQ * HDIM);
    const unsigned short* Kb = kh + bh * (TSEQ * HDIM);
    const unsigned short* Vb = vt + bh * (TSEQ * HDIM);

    // staging lane constants (source-side XOR swizzle, LDS dest linear)
    const int krow = lane >> 3;
    const int kgc  = (lane & 7) ^ krow;
    const int vrow = lane >> 4;
    const int vcc  = lane & 15;

#define STAGE(BUF, KV) do {                                                   \
    _Pragma("unroll")                                                         \
    for (int i_ = 0; i_ < 4; ++i_) {                                          \
        int cz_ = wid * 4 + i_;                       /* 0..15 */             \
        gload16(&Kb[((KV) + cz_ * 8 + krow) * 64 + kgc * 8],                  \
                &Kl[BUF][cz_ * 512]);                                         \
        int d_ = cz_ * 4 + vrow;                                              \
        int gc_ = vcc ^ (d_ & 15);                                            \
        gload16(&Vb[d_ * 2048 + (KV) + gc_ * 8], &Vl[BUF][cz_ * 512]);        \
    } } while (0)

    u16x8 qf[4];
    #pragma unroll
    for (int kf = 0; kf < 4; ++kf)
        qf[kf] = *(const u16x8*)&Qb[qg * 64 + kf * 16 + hi * 8];

    float m_r = -1e30f, l_r = 0.f;
    f32x16v Ot[2] = {};                    // O^T: d = dn*32+(r&3)+8*(r>>2)+4*hi

    STAGE(0, tlo * 128);
    int cur = 0;

    for (int t = tlo; t <= thi; ++t) {
        const int kv0 = t * 128;
        __syncthreads();

        if (t < thi) STAGE(cur ^ 1, (t + 1) * 128);

        // wave-level activity: causal top + window bottom
        if (kv0 <= qw + 31 && kv0 + 127 >= qw - Wwin) {
            const int v0 = qw - kv0;       // >= 0 (t <= c)
            int nkv2 = (v0 >> 5) + 1; if (nkv2 > 4) nkv2 = 4;
            const bool diag = (kv0 + 127 > qw);

            // S^T = K . Q (raw scores; scale folded into Q)
            f32x16v st[4];
            __builtin_amdgcn_s_setprio(1);
            #pragma unroll
            for (int kv2 = 0; kv2 < 4; ++kv2) {
                if (kv2 < nkv2) {
                    f32x16v a = {};
                    #pragma unroll
                    for (int kf = 0; kf < 4; ++kf) {
                        u16x8 ka = *(const u16x8*)&Kl[cur][(kv2 * 32 + l31) * 64 +
                                                           (((kf * 2 + hi) ^ (l31 & 7)) * 8)];
                        a = mfma32(ka, qf[kf], a);
                    }
                    st[kv2] = a;
                } else {
                    st[kv2] = (f32x16v)(-1e30f);
                }
            }
            __builtin_amdgcn_s_setprio(0);

            // causal mask on raw scores (diagonal tile only)
            if (diag) {
                #pragma unroll
                for (int kv2 = 0; kv2 < 4; ++kv2) {
                    if (kv2 < nkv2) {
                        #pragma unroll
                        for (int r = 0; r < 16; ++r) {
                            int kv = kv0 + kv2 * 32 + (r & 3) + 8 * (r >> 2) + 4 * hi;
                            if (kv > qg) st[kv2][r] = -1e30f;
                        }
                    }
                }
            }

            // raw row max (in-lane tree + cross-half swap)
            float t16[16];
            #pragma unroll
            for (int i = 0; i < 16; ++i)
                t16[i] = fmaxf(fmaxf(st[0][i], st[1][i]), fmaxf(st[2][i], st[3][i]));
            #pragma unroll
            for (int i = 0; i < 8; ++i) t16[i] = fmaxf(t16[i], t16[i + 8]);
            #pragma unroll
            for (int i = 0; i < 4; ++i) t16[i] = fmaxf(t16[i], t16[i + 4]);
            float rm = fmaxf(fmaxf(t16[0], t16[1]), fmaxf(t16[2], t16[3]));
            rm = fmaxf(rm, __shfl_xor(rm, 32, 64));

            // upper bound on biased max: raw max + largest in-tile bias
            int kvmax = kv0 + 127; if (kvmax > qw + 31) kvmax = qw + 31;
            float cand = rm + slope2 * (float)(kvmax - 2047);

            // defer-max: rescale only when the bound moved by > 8
            if (!__all(cand - m_r <= 8.0f)) {
                float mn = fmaxf(m_r, cand);
                float alpha = exp2f(m_r - mn);
                m_r = mn;
                l_r *= alpha;
                Ot[0] *= alpha;
                Ot[1] *= alpha;
            }

            // p = exp2(raw + bias - m), bias folded; then row sum
            #pragma unroll
            for (int kv2 = 0; kv2 < 4; ++kv2) {
                if (kv2 < nkv2) {
                    float base2 = slope2 * (float)(kv0 + kv2 * 32 + 4 * hi - 2047) - m_r;
                    #pragma unroll
                    for (int r = 0; r < 16; ++r) {
                        float koff = (float)((r & 3) + 8 * (r >> 2));
                        st[kv2][r] = exp2f(st[kv2][r] + fmaf(slope2, koff, base2));
                    }
                } else {
                    st[kv2] = (f32x16v)(0.f);
                }
            }
            float s16[16];
            #pragma unroll
            for (int i = 0; i < 16; ++i)
                s16[i] = (st[0][i] + st[1][i]) + (st[2][i] + st[3][i]);
            #pragma unroll
            for (int i = 0; i < 8; ++i) s16[i] += s16[i + 8];
            #pragma unroll
            for (int i = 0; i < 4; ++i) s16[i] += s16[i + 4];
            float rs = (s16[0] + s16[1]) + (s16[2] + s16[3]);
            rs += __shfl_xor(rs, 32, 64);
            l_r += rs;

            // pack P^T to bf16 pairs (active frags only)
            unsigned pku[4][8];
            #pragma unroll
            for (int kv2 = 0; kv2 < 4; ++kv2) {
                if (kv2 < nkv2) {
                    #pragma unroll
                    for (int idx = 0; idx < 8; ++idx) {
                        unsigned lo2 = __builtin_bit_cast(unsigned short, (__bf16)st[kv2][2 * idx]);
                        unsigned hh = __builtin_bit_cast(unsigned short, (__bf16)st[kv2][2 * idx + 1]);
                        pku[kv2][idx] = lo2 | (hh << 16);
                    }
                }
            }

            // O^T += V^T . P^T
            __builtin_amdgcn_s_setprio(1);
            #pragma unroll
            for (int kf = 0; kf < 8; ++kf) {
                if ((kf >> 1) < nkv2) {
                    const int kv2 = kf >> 1, base = 4 * (kf & 1);
                    unsigned s0 = hi ? pku[kv2][base + 0] : pku[kv2][base + 2];
                    unsigned s1 = hi ? pku[kv2][base + 1] : pku[kv2][base + 3];
                    unsigned r0 = __shfl_xor(s0, 32, 64);
                    unsigned r1 = __shfl_xor(s1, 32, 64);
                    u32x4 w;
                    w[0] = hi ? r0 : pku[kv2][base + 0];
                    w[1] = hi ? r1 : pku[kv2][base + 1];
                    w[2] = hi ? pku[kv2][base + 2] : r0;
                    w[3] = hi ? pku[kv2][base + 3] : r1;
                    u16x8 pb = __builtin_bit_cast(u16x8, w);
                    #pragma unroll
                    for (int dn = 0; dn < 2; ++dn) {
                        u16x8 va = *(const u16x8*)&Vl[cur][(dn * 32 + l31) * 128 +
                                                           (((kf * 2 + hi) ^ (l31 & 15)) * 8)];
                        Ot[dn] = mfma32(va, pb, Ot[dn]);
                    }
                }
            }
            __builtin_amdgcn_s_setprio(0);
        }

        cur ^= 1;
    }

    if (split) {
        // write unnormalized bf16 O-partial + (m,l)
        const int slot = ((b * 6 + (h - 10)) * 8 + (c - 8)) * 2 + seg;
        unsigned short* P = part + slot * 8192;
        const int qloc = wid * 32 + l31;
        #pragma unroll
        for (int dn = 0; dn < 2; ++dn)
            #pragma unroll
            for (int rq = 0; rq < 4; ++rq) {
                u16x4 o;
                #pragma unroll
                for (int jj = 0; jj < 4; ++jj)
                    o[jj] = f2bf(Ot[dn][rq * 4 + jj]);
                int d = dn * 32 + 8 * rq + 4 * hi;
                *(u16x4*)&P[qloc * 64 + d] = o;
            }
        mlb[(slot * 128 + qloc) * 2 + 0] = m_r;
        mlb[(slot * 128 + qloc) * 2 + 1] = l_r;
    } else {
        float rl = 1.0f / l_r;
        #pragma unroll
        for (int dn = 0; dn < 2; ++dn)
            #pragma unroll
            for (int rq = 0; rq < 4; ++rq) {
                u16x4 o;
                #pragma unroll
                for (int jj = 0; jj < 4; ++jj)
                    o[jj] = f2bf(Ot[dn][rq * 4 + jj] * rl);
                int d = dn * 32 + 8 * rq + 4 * hi;
                *(u16x4*)&aout[(b * 2048 + qg) * 1024 + h * 64 + d] = o;
            }
    }
#undef STAGE
}

// ---------------------------------------------------------------------------
// Kernel 3b: merge the two segments of split tasks.
// Grid (8 = c-8, 64 = b*h), 256 thr: thread -> (q = tid>>1, 32-d half).
// ---------------------------------------------------------------------------
__global__ __launch_bounds__(256) void combine2(
    const unsigned short* __restrict__ part, const float* __restrict__ mlb,
    unsigned short* __restrict__ aout)
{
    const int c  = 8 + blockIdx.x;
    const int bh = blockIdx.y;
    const int h  = bh & 15, b = bh >> 4;
    if (h < 10) return;

    const float slope2 = exp2f(-0.5f * (float)(h + 1)) * LOG2E;
    const int   Wwin   = (int)ceilf(40.0f / slope2);
    int t0i = c * 128 - Wwin;
    const int t0 = (t0i > 0) ? (t0i >> 7) : 0;
    const int n  = c - t0 + 1;
    if (n <= 9) return;                    // not split

    const int slot0 = ((b * 6 + (h - 10)) * 8 + (c - 8)) * 2;
    const int tid = threadIdx.x;
    const int q  = tid >> 1;
    const int dh = (tid & 1) * 32;

    float m0 = mlb[(slot0 * 128 + q) * 2 + 0];
    float l0 = mlb[(slot0 * 128 + q) * 2 + 1];
    float m1 = mlb[((slot0 + 1) * 128 + q) * 2 + 0];
    float l1 = mlb[((slot0 + 1) * 128 + q) * 2 + 1];
    float M  = fmaxf(m0, m1);
    float w0 = exp2f(m0 - M), w1 = exp2f(m1 - M);
    float rl = 1.0f / (l0 * w0 + l1 * w1);

    const unsigned short* P0 = part + slot0 * 8192 + q * 64 + dh;
    const unsigned short* P1 = part + (slot0 + 1) * 8192 + q * 64 + dh;
    unsigned short* dst = aout + (b * 2048 + c * 128 + q) * 1024 + h * 64 + dh;

    #pragma unroll
    for (int i = 0; i < 4; ++i) {
        u16x8 a0 = *(const u16x8*)&P0[i * 8];
        u16x8 a1 = *(const u16x8*)&P1[i * 8];
        u16x8 o;
        #pragma unroll
        for (int e = 0; e < 8; ++e)
            o[e] = f2bf((bf2f(a0[e]) * w0 + bf2f(a1[e]) * w1) * rl);
        *(u16x8*)&dst[i * 8] = o;
    }
}

// ---------------------------------------------------------------------------
extern "C" void kernel_launch(void* const* d_in, const int* in_sizes, int n_in,
                              void* d_out, int out_size, void* d_ws, size_t ws_size,
                              hipStream_t stream)
{
    const float* x  = (const float*)d_in[0];
    const float* Wq = (const float*)d_in[1];
    const float* Wk = (const float*)d_in[2];
    const float* Wv = (const float*)d_in[3];
    const float* Wo = (const float*)d_in[4];

    unsigned short* ws = (unsigned short*)d_ws;
    unsigned short* wb = ws;                       // 4 x 1M bf16 (W^T: q,k,v,o)
    unsigned short* xb = ws + 4194304;             // 8M bf16
    unsigned short* qh = ws + 12582912;
    unsigned short* kh = qh + 8388608;
    unsigned short* vt = kh + 8388608;
    unsigned short* part = ws + 37748736;          // 384 x 8192 u16 O-partials
    float* mlb = (float*)(ws + 40894464);          // 384 x 128 x 2 f32
    unsigned short* ao = xb;                       // alias: xb dead after QKV GEMM

    castx<<<dim3(8192), dim3(256), 0, stream>>>(x, xb);
    wtcast<<<dim3(16, 16, 4), dim3(256), 0, stream>>>(Wq, Wk, Wv, Wo, wb);
    gemm_gl<0><<<dim3(8, 64, 3), dim3(256), 0, stream>>>(xb, wb, qh, (float*)nullptr);
    attn128s<<<dim3(32, 64), dim3(256), 0, stream>>>(qh, kh, vt, part, mlb, ao);
    combine2<<<dim3(8, 64), dim3(256), 0, stream>>>(part, mlb, ao);
    gemm_gl<1><<<dim3(8, 64, 1), dim3(256), 0, stream>>>(
        ao, wb + 3 * 1048576, (unsigned short*)nullptr, (float*)d_out);
}

// Round 12
// 297.536 us; speedup vs baseline: 1.3371x; 1.3371x over previous
//
#include <hip/hip_runtime.h>
#include <hip/hip_bf16.h>

// Problem constants: B=4, T=2048, C=1024, NH=16, HD=64
#define TSEQ   2048
#define CDIM   1024
#define NHEAD  16
#define HDIM   64

typedef float f32x4  __attribute__((ext_vector_type(4)));
typedef float f32x16v __attribute__((ext_vector_type(16)));
typedef __bf16 bf16x8 __attribute__((ext_vector_type(8)));
typedef unsigned short u16x8 __attribute__((ext_vector_type(8)));
typedef unsigned short u16x4 __attribute__((ext_vector_type(4)));
typedef unsigned int   u32x4 __attribute__((ext_vector_type(4)));

#define QSCALE 0.18033688011112042f   // 0.125 * log2(e)
#define LOG2E  1.4426950408889634f

static __device__ __forceinline__ unsigned short f2bf(float f) {
    unsigned u = __builtin_bit_cast(unsigned, f);
    unsigned r = u + 0x7FFFu + ((u >> 16) & 1u);   // round-to-nearest-even
    return (unsigned short)(r >> 16);
}
static __device__ __forceinline__ float bf2f(unsigned short u) {
    unsigned v = ((unsigned)u) << 16;
    return __builtin_bit_cast(float, v);
}

static __device__ __forceinline__ f32x4 mfma16(u16x8 a, u16x8 b, f32x4 c) {
    return __builtin_amdgcn_mfma_f32_16x16x32_bf16(
        __builtin_bit_cast(bf16x8, a), __builtin_bit_cast(bf16x8, b), c, 0, 0, 0);
}
static __device__ __forceinline__ f32x16v mfma32(u16x8 a, u16x8 b, f32x16v c) {
    return __builtin_amdgcn_mfma_f32_32x32x16_bf16(
        __builtin_bit_cast(bf16x8, a), __builtin_bit_cast(bf16x8, b), c, 0, 0, 0);
}

static __device__ __forceinline__ void gload16(const void* g, void* l) {
    __builtin_amdgcn_global_load_lds(
        (const __attribute__((address_space(1))) unsigned int*)g,
        (__attribute__((address_space(3))) unsigned int*)l, 16, 0, 0);
}

// Workspace layout (u16 units):
//   wb   : 0        .. 4194303   (W^T q,k,v,o bf16, 1M each -- TRANSPOSED [n][k])
//   xb   : 4194304  .. 12582911  (x bf16, 8M) -- reused as `ao` after QKV GEMM
//   qh   : 12582912 .. 20971519  ([B,NH,T,HD] bf16, pre-scaled by QSCALE)
//   kh   : 20971520 .. 29359103  ([B,NH,T,HD] bf16)
//   vt   : 29359104 .. 37748735  ([B,NH,HD,T] bf16 -- V TRANSPOSED)
//   part : 37748736 .. 40894463  (384 slots x 128x64 bf16 O-partials)
//   mlb  : 40894464 .. 41091071  (384 x 128 x 2 f32 (m,l))   -- total 82.2 MB

// ---------------------------------------------------------------------------
__global__ __launch_bounds__(256) void castx(
    const float* __restrict__ x, unsigned short* __restrict__ xb)
{
    int t = blockIdx.x * 256 + threadIdx.x;   // float4 index, < 2097152
    f32x4 v = *(const f32x4*)&x[t * 4];
    u16x4 o;
    o[0] = f2bf(v[0]); o[1] = f2bf(v[1]); o[2] = f2bf(v[2]); o[3] = f2bf(v[3]);
    *(u16x4*)&xb[t * 4] = o;
}

// ---------------------------------------------------------------------------
__global__ __launch_bounds__(256) void wtcast(
    const float* __restrict__ wq, const float* __restrict__ wk,
    const float* __restrict__ wv, const float* __restrict__ wo,
    unsigned short* __restrict__ wt)
{
    __shared__ unsigned short t[64 * 72];
    const int z = blockIdx.z;
    const float* src = (z == 0) ? wq : (z == 1) ? wk : (z == 2) ? wv : wo;
    const int k0 = blockIdx.x * 64, n0 = blockIdx.y * 64, tid = threadIdx.x;

    #pragma unroll
    for (int i = 0; i < 4; ++i) {
        int idx = i * 256 + tid;
        int r = idx >> 4, c4 = idx & 15;
        f32x4 v = *(const f32x4*)&src[(k0 + r) * 1024 + n0 + c4 * 4];
        u16x4 o;
        o[0] = f2bf(v[0]); o[1] = f2bf(v[1]); o[2] = f2bf(v[2]); o[3] = f2bf(v[3]);
        *(u16x4*)&t[r * 72 + c4 * 4] = o;
    }
    __syncthreads();
    #pragma unroll
    for (int i = 0; i < 2; ++i) {
        int idx = i * 256 + tid;
        int n = idx >> 3, k8 = idx & 7;
        u16x8 o;
        #pragma unroll
        for (int e = 0; e < 8; ++e) o[e] = t[(k8 * 8 + e) * 72 + n];
        *(u16x8*)&wt[z * 1048576 + (n0 + n) * 1024 + k0 + k8 * 8] = o;
    }
}

// ---------------------------------------------------------------------------
template<int MODE>
__global__ __launch_bounds__(256) void gemm_gl(
    const unsigned short* __restrict__ A, const unsigned short* __restrict__ WT,
    unsigned short* __restrict__ outb, float* __restrict__ outf)
{
    __shared__ __align__(16) unsigned short Al[128 * 64];
    __shared__ __align__(16) unsigned short Bl[128 * 64];

    const int tid  = threadIdx.x;
    const int z    = blockIdx.z;
    const int m0   = blockIdx.y * 128;
    const int n0   = blockIdx.x * 128;
    const unsigned short* W = WT + (MODE == 0 ? z * 1048576 : 0);

    const int wid  = tid >> 6, lane = tid & 63;
    const int wr   = (wid >> 1) * 64, wc = (wid & 1) * 64;
    const int lrow = lane & 15, lk = (lane >> 4) * 8;

    f32x4 acc[4][4] = {};

    for (int kt = 0; kt < 16; ++kt) {
        __syncthreads();
        #pragma unroll
        for (int c = 0; c < 4; ++c) {
            int cz = wid * 4 + c;
            int row = cz * 8 + (lane >> 3), col = (lane & 7) * 8;
            gload16(&A[(m0 + row) * 1024 + kt * 64 + col], &Al[cz * 512]);
            gload16(&W[(n0 + row) * 1024 + kt * 64 + col], &Bl[cz * 512]);
        }
        __syncthreads();
        #pragma unroll
        for (int ks = 0; ks < 2; ++ks) {
            u16x8 af[4], bfr[4];
            #pragma unroll
            for (int m = 0; m < 4; ++m)
                af[m] = *(const u16x8*)&Al[(wr + m * 16 + lrow) * 64 + ks * 32 + lk];
            #pragma unroll
            for (int n = 0; n < 4; ++n)
                bfr[n] = *(const u16x8*)&Bl[(wc + n * 16 + lrow) * 64 + ks * 32 + lk];
            #pragma unroll
            for (int m = 0; m < 4; ++m)
                #pragma unroll
                for (int n = 0; n < 4; ++n)
                    acc[m][n] = mfma16(af[m], bfr[n], acc[m][n]);
        }
    }

    const int g = lane >> 4;
    #pragma unroll
    for (int m = 0; m < 4; ++m)
        #pragma unroll
        for (int n = 0; n < 4; ++n)
            #pragma unroll
            for (int j = 0; j < 4; ++j) {
                int grow = m0 + wr + m * 16 + g * 4 + j;
                int gcol = n0 + wc + n * 16 + lrow;
                float val = acc[m][n][j];
                if (MODE == 0) {
                    int b = grow >> 11, t = grow & 2047;
                    int h = gcol >> 6,  d = gcol & 63;
                    if (z == 0) val *= QSCALE;
                    if (z == 2)
                        outb[z * 8388608 + (((b << 4) + h) * 64 + d) * 2048 + t] = f2bf(val);
                    else
                        outb[z * 8388608 + (((b << 4) + h) * 2048 + t) * 64 + d] = f2bf(val);
                } else {
                    outf[grow * 1024 + gcol] = val;
                }
            }
}

// ---------------------------------------------------------------------------
// Kernel 3: split-KV flash attention in the r10 regime: KVBLK=64, 32 KB LDS
// (4-5 blocks/CU), ALL ~1216 real blocks co-resident at t=0, so makespan =
// longest chain. Chains capped at 16 tiles: task (bh, c) with windowed range
// n > 16 tiles (exactly h>=10 && c>=8) splits into two <=16-tile segments
// writing unnormalized bf16 O-partials + (m,l); combine2 merges. Body = r10
// verbatim (XOR-swizzled global_load_lds, swapped QK^T 32x32, raw-max bound,
// fused bias-exp2, defer-max, per-wave window/diag gating).
// Grid (32 = c x seg heavy-first, 64 = b*h). 256 thr = 4 waves x 32 q-rows.
// ---------------------------------------------------------------------------
__global__ __launch_bounds__(256) void attn64s(
    const unsigned short* __restrict__ qh, const unsigned short* __restrict__ kh,
    const unsigned short* __restrict__ vt, unsigned short* __restrict__ part,
    float* __restrict__ mlb, unsigned short* __restrict__ aout)
{
    __shared__ __align__(16) unsigned short Kl[2][64 * 64];   // 8 KB each
    __shared__ __align__(16) unsigned short Vl[2][64 * 64];   // V^T: [d][kv]

    const int xx  = blockIdx.x;            // 0..31
    const int c   = 15 - (xx >> 1);        // heavy q-chunks first
    const int seg = xx & 1;
    const int bh  = blockIdx.y;
    const int h   = bh & 15, b = bh >> 4;

    const float slope2 = exp2f(-0.5f * (float)(h + 1)) * LOG2E;
    const int   Wwin   = (int)ceilf(40.0f / slope2);     // ALiBi window

    int blo = c * 128 - Wwin;
    const int t_start = (blo > 0) ? (blo >> 6) : 0;
    const int t_last  = 2 * c + 1;
    const int n       = t_last - t_start + 1;
    const bool split  = (n > 16);
    if (!split && seg) return;

    int tlo, thi;
    if (split) {
        int h1 = (n + 1) >> 1;             // seg0 length (<= 16)
        tlo = seg ? (t_start + h1) : t_start;
        thi = seg ? t_last : (t_start + h1 - 1);
    } else { tlo = t_start; thi = t_last; }

    const int tid = threadIdx.x, wid = tid >> 6, lane = tid & 63;
    const int l31 = lane & 31, hi = lane >> 5;
    const int qw = c * 128 + wid * 32;     // wave's first q row
    const int qg = qw + l31;               // lane's q row

    const unsigned short* Qb = qh + bh * (TSEQ * HDIM);
    const unsigned short* Kb = kh + bh * (TSEQ * HDIM);
    const unsigned short* Vb = vt + bh * (TSEQ * HDIM);  // [d][t]

    // per-wave compute gating
    int wlo = qw - Wwin;
    const int w_start = (wlo > 0) ? (wlo >> 6) : 0;
    const int w_diag  = (qw + 31) >> 6;

    // staging lane constants (source-side XOR swizzle, LDS dest linear)
    const int krow = lane >> 3;            // row within 8-row chunk (K) / d (V)
    const int kgc  = (lane & 7) ^ krow;    // swizzled 16B chunk index

#define STAGE(BUF, KV) do {                                                   \
    _Pragma("unroll")                                                         \
    for (int i_ = 0; i_ < 2; ++i_) {                                          \
        int cz_ = wid * 2 + i_;                       /* 0..7 */              \
        gload16(&Kb[((KV) + cz_ * 8 + krow) * 64 + kgc * 8],                  \
                &Kl[BUF][cz_ * 512]);                                         \
        gload16(&Vb[(cz_ * 8 + krow) * 2048 + (KV) + kgc * 8],                \
                &Vl[BUF][cz_ * 512]);                                         \
    } } while (0)

    // Q B-frags: col = l31 -> q row, k = kf*16 + hi*8 + i (pre-scaled)
    u16x8 qf[4];
    #pragma unroll
    for (int kf = 0; kf < 4; ++kf)
        qf[kf] = *(const u16x8*)&Qb[qg * 64 + kf * 16 + hi * 8];

    float m_r = -1e30f, l_r = 0.f;
    f32x16v Ot[2] = {};                    // O^T: d = dn*32+(r&3)+8*(r>>2)+4*hi

    STAGE(0, tlo * 64);                    // prologue
    int cur = 0;

    for (int t = tlo; t <= thi; ++t) {
        const int kv0 = t * 64;
        __syncthreads();                   // drains this tile's loads

        if (t < thi) STAGE(cur ^ 1, (t + 1) * 64);

        if (t >= w_start && t <= w_diag) {
            // active fragment count (diagonal skip): d0 = qw+31-kv0 >= 0 here
            const int  d0   = qw + 31 - kv0;
            int nkv2 = (d0 >> 5) + 1; if (nkv2 > 2) nkv2 = 2;
            const bool diag = (kv0 + 63 > qw);

            // S^T = K . Q (raw scores, scale pre-folded into Q)
            f32x16v st[2];
            __builtin_amdgcn_s_setprio(1);
            #pragma unroll
            for (int kv2 = 0; kv2 < 2; ++kv2) {
                if (kv2 < nkv2) {
                    f32x16v a = {};
                    #pragma unroll
                    for (int kf = 0; kf < 4; ++kf) {
                        u16x8 ka = *(const u16x8*)&Kl[cur][(kv2 * 32 + l31) * 64 +
                                                           (((kf * 2 + hi) ^ (l31 & 7)) * 8)];
                        a = mfma32(ka, qf[kf], a);
                    }
                    st[kv2] = a;
                } else {
                    st[kv2] = (f32x16v)(-1e30f);
                }
            }
            __builtin_amdgcn_s_setprio(0);

            // causal mask on raw scores (diagonal tiles only)
            if (diag) {
                #pragma unroll
                for (int kv2 = 0; kv2 < 2; ++kv2) {
                    if (kv2 < nkv2) {
                        #pragma unroll
                        for (int r = 0; r < 16; ++r) {
                            int kv = kv0 + kv2 * 32 + (r & 3) + 8 * (r >> 2) + 4 * hi;
                            if (kv > qg) st[kv2][r] = -1e30f;
                        }
                    }
                }
            }

            // raw-score row max (in-lane tree + cross-half swap)
            float t16[16];
            #pragma unroll
            for (int i = 0; i < 16; ++i) t16[i] = fmaxf(st[0][i], st[1][i]);
            #pragma unroll
            for (int i = 0; i < 8; ++i) t16[i] = fmaxf(t16[i], t16[i + 8]);
            #pragma unroll
            for (int i = 0; i < 4; ++i) t16[i] = fmaxf(t16[i], t16[i + 4]);
            float rm = fmaxf(fmaxf(t16[0], t16[1]), fmaxf(t16[2], t16[3]));
            rm = fmaxf(rm, __shfl_xor(rm, 32, 64));

            // upper bound on biased max: raw max + largest in-tile bias
            int kvmax = kv0 + 63; if (kvmax > qw + 31) kvmax = qw + 31;
            float cand = rm + slope2 * (float)(kvmax - 2047);

            // defer-max: rescale only when the bound moved by > 8
            if (!__all(cand - m_r <= 8.0f)) {
                float mn = fmaxf(m_r, cand);
                float alpha = exp2f(m_r - mn);
                m_r = mn;
                l_r *= alpha;
                Ot[0] *= alpha;
                Ot[1] *= alpha;
            }

            // p = exp2(raw + bias - m) in one pass; bias folded into base2
            #pragma unroll
            for (int kv2 = 0; kv2 < 2; ++kv2) {
                if (kv2 < nkv2) {
                    float base2 = slope2 * (float)(kv0 + kv2 * 32 + 4 * hi - 2047) - m_r;
                    #pragma unroll
                    for (int r = 0; r < 16; ++r) {
                        float koff = (float)((r & 3) + 8 * (r >> 2));
                        st[kv2][r] = exp2f(st[kv2][r] + fmaf(slope2, koff, base2));
                    }
                } else {
                    st[kv2] = (f32x16v)(0.f);
                }
            }

            // row sum (in-lane tree + cross-half add)
            float s16[16];
            #pragma unroll
            for (int i = 0; i < 16; ++i) s16[i] = st[0][i] + st[1][i];
            #pragma unroll
            for (int i = 0; i < 8; ++i) s16[i] += s16[i + 8];
            #pragma unroll
            for (int i = 0; i < 4; ++i) s16[i] += s16[i + 4];
            float rs = (s16[0] + s16[1]) + (s16[2] + s16[3]);
            rs += __shfl_xor(rs, 32, 64);
            l_r += rs;

            // pack P^T to bf16 pairs (active frags only)
            unsigned pku[2][8];
            #pragma unroll
            for (int kv2 = 0; kv2 < 2; ++kv2) {
                if (kv2 < nkv2) {
                    #pragma unroll
                    for (int idx = 0; idx < 8; ++idx) {
                        unsigned lo2 = __builtin_bit_cast(unsigned short, (__bf16)st[kv2][2 * idx]);
                        unsigned hh = __builtin_bit_cast(unsigned short, (__bf16)st[kv2][2 * idx + 1]);
                        pku[kv2][idx] = lo2 | (hh << 16);
                    }
                }
            }

            // O^T += V^T . P^T (skip masked kf pairs)
            __builtin_amdgcn_s_setprio(1);
            #pragma unroll
            for (int kf = 0; kf < 4; ++kf) {
                if ((kf >> 1) < nkv2) {
                    const int kv2 = kf >> 1, base = 4 * (kf & 1);
                    unsigned s0 = hi ? pku[kv2][base + 0] : pku[kv2][base + 2];
                    unsigned s1 = hi ? pku[kv2][base + 1] : pku[kv2][base + 3];
                    unsigned r0 = __shfl_xor(s0, 32, 64);
                    unsigned r1 = __shfl_xor(s1, 32, 64);
                    u32x4 w;
                    w[0] = hi ? r0 : pku[kv2][base + 0];
                    w[1] = hi ? r1 : pku[kv2][base + 1];
                    w[2] = hi ? pku[kv2][base + 2] : r0;
                    w[3] = hi ? pku[kv2][base + 3] : r1;
                    u16x8 pb = __builtin_bit_cast(u16x8, w);
                    #pragma unroll
                    for (int dn = 0; dn < 2; ++dn) {
                        u16x8 va = *(const u16x8*)&Vl[cur][(dn * 32 + l31) * 64 +
                                                           (((kf * 2 + hi) ^ (l31 & 7)) * 8)];
                        Ot[dn] = mfma32(va, pb, Ot[dn]);
                    }
                }
            }
            __builtin_amdgcn_s_setprio(0);
        }

        cur ^= 1;
    }

    if (split) {
        // write unnormalized bf16 O-partial + (m,l)
        const int slot = ((b * 6 + (h - 10)) * 8 + (c - 8)) * 2 + seg;
        unsigned short* P = part + slot * 8192;
        const int qloc = wid * 32 + l31;
        #pragma unroll
        for (int dn = 0; dn < 2; ++dn)
            #pragma unroll
            for (int rq = 0; rq < 4; ++rq) {
                u16x4 o;
                #pragma unroll
                for (int jj = 0; jj < 4; ++jj)
                    o[jj] = f2bf(Ot[dn][rq * 4 + jj]);
                int d = dn * 32 + 8 * rq + 4 * hi;
                *(u16x4*)&P[qloc * 64 + d] = o;
            }
        mlb[(slot * 128 + qloc) * 2 + 0] = m_r;
        mlb[(slot * 128 + qloc) * 2 + 1] = l_r;
    } else {
        float rl = 1.0f / l_r;
        #pragma unroll
        for (int dn = 0; dn < 2; ++dn)
            #pragma unroll
            for (int rq = 0; rq < 4; ++rq) {
                u16x4 o;
                #pragma unroll
                for (int jj = 0; jj < 4; ++jj)
                    o[jj] = f2bf(Ot[dn][rq * 4 + jj] * rl);
                int d = dn * 32 + 8 * rq + 4 * hi;
                *(u16x4*)&aout[(b * 2048 + qg) * 1024 + h * 64 + d] = o;
            }
    }
#undef STAGE
}

// ---------------------------------------------------------------------------
// Kernel 3b: merge the two segments of split tasks (h>=10, c>=8, n>16).
// Grid (8 = c-8, 64 = b*h), 256 thr: thread -> (q = tid>>1, 32-d half).
// ---------------------------------------------------------------------------
__global__ __launch_bounds__(256) void combine2(
    const unsigned short* __restrict__ part, const float* __restrict__ mlb,
    unsigned short* __restrict__ aout)
{
    const int c  = 8 + blockIdx.x;
    const int bh = blockIdx.y;
    const int h  = bh & 15, b = bh >> 4;
    if (h < 10) return;

    const float slope2 = exp2f(-0.5f * (float)(h + 1)) * LOG2E;
    const int   Wwin   = (int)ceilf(40.0f / slope2);
    int blo = c * 128 - Wwin;
    const int t_start = (blo > 0) ? (blo >> 6) : 0;
    const int n = (2 * c + 1) - t_start + 1;
    if (n <= 16) return;                   // not split

    const int slot0 = ((b * 6 + (h - 10)) * 8 + (c - 8)) * 2;
    const int tid = threadIdx.x;
    const int q  = tid >> 1;
    const int dh = (tid & 1) * 32;

    float m0 = mlb[(slot0 * 128 + q) * 2 + 0];
    float l0 = mlb[(slot0 * 128 + q) * 2 + 1];
    float m1 = mlb[((slot0 + 1) * 128 + q) * 2 + 0];
    float l1 = mlb[((slot0 + 1) * 128 + q) * 2 + 1];
    float M  = fmaxf(m0, m1);
    float w0 = exp2f(m0 - M), w1 = exp2f(m1 - M);
    float rl = 1.0f / (l0 * w0 + l1 * w1);

    const unsigned short* P0 = part + slot0 * 8192 + q * 64 + dh;
    const unsigned short* P1 = part + (slot0 + 1) * 8192 + q * 64 + dh;
    unsigned short* dst = aout + (b * 2048 + c * 128 + q) * 1024 + h * 64 + dh;

    #pragma unroll
    for (int i = 0; i < 4; ++i) {
        u16x8 a0 = *(const u16x8*)&P0[i * 8];
        u16x8 a1 = *(const u16x8*)&P1[i * 8];
        u16x8 o;
        #pragma unroll
        for (int e = 0; e < 8; ++e)
            o[e] = f2bf((bf2f(a0[e]) * w0 + bf2f(a1[e]) * w1) * rl);
        *(u16x8*)&dst[i * 8] = o;
    }
}

// ---------------------------------------------------------------------------
extern "C" void kernel_launch(void* const* d_in, const int* in_sizes, int n_in,
                              void* d_out, int out_size, void* d_ws, size_t ws_size,
                              hipStream_t stream)
{
    const float* x  = (const float*)d_in[0];
    const float* Wq = (const float*)d_in[1];
    const float* Wk = (const float*)d_in[2];
    const float* Wv = (const float*)d_in[3];
    const float* Wo = (const float*)d_in[4];

    unsigned short* ws = (unsigned short*)d_ws;
    unsigned short* wb = ws;                       // 4 x 1M bf16 (W^T: q,k,v,o)
    unsigned short* xb = ws + 4194304;             // 8M bf16
    unsigned short* qh = ws + 12582912;
    unsigned short* kh = qh + 8388608;
    unsigned short* vt = kh + 8388608;
    unsigned short* part = ws + 37748736;          // 384 x 8192 u16 O-partials
    float* mlb = (float*)(ws + 40894464);          // 384 x 128 x 2 f32
    unsigned short* ao = xb;                       // alias: xb dead after QKV GEMM

    castx<<<dim3(8192), dim3(256), 0, stream>>>(x, xb);
    wtcast<<<dim3(16, 16, 4), dim3(256), 0, stream>>>(Wq, Wk, Wv, Wo, wb);
    gemm_gl<0><<<dim3(8, 64, 3), dim3(256), 0, stream>>>(xb, wb, qh, (float*)nullptr);
    attn64s<<<dim3(32, 64), dim3(256), 0, stream>>>(qh, kh, vt, part, mlb, ao);
    combine2<<<dim3(8, 64), dim3(256), 0, stream>>>(part, mlb, ao);
    gemm_gl<1><<<dim3(8, 64, 1), dim3(256), 0, stream>>>(
        ao, wb + 3 * 1048576, (unsigned short*)nullptr, (float*)d_out);
}

// Round 13
// 228.921 us; speedup vs baseline: 1.7379x; 1.2997x over previous
//
#include <hip/hip_runtime.h>
#include <hip/hip_bf16.h>

// Problem constants: B=4, T=2048, C=1024, NH=16, HD=64
#define TSEQ   2048
#define CDIM   1024
#define NHEAD  16
#define HDIM   64

typedef float f32x4  __attribute__((ext_vector_type(4)));
typedef float f32x16v __attribute__((ext_vector_type(16)));
typedef __bf16 bf16x8 __attribute__((ext_vector_type(8)));
typedef unsigned short u16x8 __attribute__((ext_vector_type(8)));
typedef unsigned short u16x4 __attribute__((ext_vector_type(4)));
typedef unsigned int   u32x4 __attribute__((ext_vector_type(4)));

#define QSCALE 0.18033688011112042f   // 0.125 * log2(e)
#define LOG2E  1.4426950408889634f

static __device__ __forceinline__ unsigned short f2bf(float f) {
    unsigned u = __builtin_bit_cast(unsigned, f);
    unsigned r = u + 0x7FFFu + ((u >> 16) & 1u);   // round-to-nearest-even
    return (unsigned short)(r >> 16);
}

static __device__ __forceinline__ f32x4 mfma16(u16x8 a, u16x8 b, f32x4 c) {
    return __builtin_amdgcn_mfma_f32_16x16x32_bf16(
        __builtin_bit_cast(bf16x8, a), __builtin_bit_cast(bf16x8, b), c, 0, 0, 0);
}
static __device__ __forceinline__ f32x16v mfma32(u16x8 a, u16x8 b, f32x16v c) {
    return __builtin_amdgcn_mfma_f32_32x32x16_bf16(
        __builtin_bit_cast(bf16x8, a), __builtin_bit_cast(bf16x8, b), c, 0, 0, 0);
}

static __device__ __forceinline__ void gload16(const void* g, void* l) {
    __builtin_amdgcn_global_load_lds(
        (const __attribute__((address_space(1))) unsigned int*)g,
        (__attribute__((address_space(3))) unsigned int*)l, 16, 0, 0);
}

// Workspace layout (u16 units):
//   wb : 0        .. 4194303   (W^T q,k,v,o bf16, 1M each -- TRANSPOSED [n][k])
//   xb : 4194304  .. 12582911  (x bf16, 8M) -- reused as `ao` after QKV GEMM
//   qh : 12582912 .. 20971519  ([B,NH,T,HD] bf16, pre-scaled by QSCALE)
//   kh : 20971520 .. 29359103  ([B,NH,T,HD] bf16)
//   vt : 29359104 .. 37748735  ([B,NH,HD,T] bf16 -- V TRANSPOSED)

// ---------------------------------------------------------------------------
__global__ __launch_bounds__(256) void castx(
    const float* __restrict__ x, unsigned short* __restrict__ xb)
{
    int t = blockIdx.x * 256 + threadIdx.x;   // float4 index, < 2097152
    f32x4 v = *(const f32x4*)&x[t * 4];
    u16x4 o;
    o[0] = f2bf(v[0]); o[1] = f2bf(v[1]); o[2] = f2bf(v[2]); o[3] = f2bf(v[3]);
    *(u16x4*)&xb[t * 4] = o;
}

// ---------------------------------------------------------------------------
__global__ __launch_bounds__(256) void wtcast(
    const float* __restrict__ wq, const float* __restrict__ wk,
    const float* __restrict__ wv, const float* __restrict__ wo,
    unsigned short* __restrict__ wt)
{
    __shared__ unsigned short t[64 * 72];
    const int z = blockIdx.z;
    const float* src = (z == 0) ? wq : (z == 1) ? wk : (z == 2) ? wv : wo;
    const int k0 = blockIdx.x * 64, n0 = blockIdx.y * 64, tid = threadIdx.x;

    #pragma unroll
    for (int i = 0; i < 4; ++i) {
        int idx = i * 256 + tid;
        int r = idx >> 4, c4 = idx & 15;
        f32x4 v = *(const f32x4*)&src[(k0 + r) * 1024 + n0 + c4 * 4];
        u16x4 o;
        o[0] = f2bf(v[0]); o[1] = f2bf(v[1]); o[2] = f2bf(v[2]); o[3] = f2bf(v[3]);
        *(u16x4*)&t[r * 72 + c4 * 4] = o;
    }
    __syncthreads();
    #pragma unroll
    for (int i = 0; i < 2; ++i) {
        int idx = i * 256 + tid;
        int n = idx >> 3, k8 = idx & 7;
        u16x8 o;
        #pragma unroll
        for (int e = 0; e < 8; ++e) o[e] = t[(k8 * 8 + e) * 72 + n];
        *(u16x8*)&wt[z * 1048576 + (n0 + n) * 1024 + k0 + k8 * 8] = o;
    }
}

// ---------------------------------------------------------------------------
template<int MODE>
__global__ __launch_bounds__(256) void gemm_gl(
    const unsigned short* __restrict__ A, const unsigned short* __restrict__ WT,
    unsigned short* __restrict__ outb, float* __restrict__ outf)
{
    __shared__ __align__(16) unsigned short Al[128 * 64];
    __shared__ __align__(16) unsigned short Bl[128 * 64];

    const int tid  = threadIdx.x;
    const int z    = blockIdx.z;
    const int m0   = blockIdx.y * 128;
    const int n0   = blockIdx.x * 128;
    const unsigned short* W = WT + (MODE == 0 ? z * 1048576 : 0);

    const int wid  = tid >> 6, lane = tid & 63;
    const int wr   = (wid >> 1) * 64, wc = (wid & 1) * 64;
    const int lrow = lane & 15, lk = (lane >> 4) * 8;

    f32x4 acc[4][4] = {};

    for (int kt = 0; kt < 16; ++kt) {
        __syncthreads();
        #pragma unroll
        for (int c = 0; c < 4; ++c) {
            int cz = wid * 4 + c;
            int row = cz * 8 + (lane >> 3), col = (lane & 7) * 8;
            gload16(&A[(m0 + row) * 1024 + kt * 64 + col], &Al[cz * 512]);
            gload16(&W[(n0 + row) * 1024 + kt * 64 + col], &Bl[cz * 512]);
        }
        __syncthreads();
        #pragma unroll
        for (int ks = 0; ks < 2; ++ks) {
            u16x8 af[4], bfr[4];
            #pragma unroll
            for (int m = 0; m < 4; ++m)
                af[m] = *(const u16x8*)&Al[(wr + m * 16 + lrow) * 64 + ks * 32 + lk];
            #pragma unroll
            for (int n = 0; n < 4; ++n)
                bfr[n] = *(const u16x8*)&Bl[(wc + n * 16 + lrow) * 64 + ks * 32 + lk];
            #pragma unroll
            for (int m = 0; m < 4; ++m)
                #pragma unroll
                for (int n = 0; n < 4; ++n)
                    acc[m][n] = mfma16(af[m], bfr[n], acc[m][n]);
        }
    }

    const int g = lane >> 4;
    #pragma unroll
    for (int m = 0; m < 4; ++m)
        #pragma unroll
        for (int n = 0; n < 4; ++n)
            #pragma unroll
            for (int j = 0; j < 4; ++j) {
                int grow = m0 + wr + m * 16 + g * 4 + j;
                int gcol = n0 + wc + n * 16 + lrow;
                float val = acc[m][n][j];
                if (MODE == 0) {
                    int b = grow >> 11, t = grow & 2047;
                    int h = gcol >> 6,  d = gcol & 63;
                    if (z == 0) val *= QSCALE;
                    if (z == 2)
                        outb[z * 8388608 + (((b << 4) + h) * 64 + d) * 2048 + t] = f2bf(val);
                    else
                        outb[z * 8388608 + (((b << 4) + h) * 2048 + t) * 64 + d] = f2bf(val);
                } else {
                    outf[grow * 1024 + gcol] = val;
                }
            }
}

// ---------------------------------------------------------------------------
// Kernel 3: 8-wave flash attention. r6 regime (KVBLK=128 dbuf, 64 KB LDS,
// uniform paired chains, all blocks co-resident) but 512 threads/block ->
// 16 waves/CU = 4 waves/SIMD (2x r6 residency; launch_bounds(512,2) caps
// VGPR at 128 = exactly 2 blocks/CU; 2nd arg is min BLOCKS/CU per r7 evidence).
// Block j: q-chunk A = 7-j (256 rows), then chunk B = j; nt = 18 uniform.
// Body: XOR-swizzled global_load_lds, swapped QK^T 32x32, raw-max bound,
// fused bias-exp2, defer-max, nkv2 diag skip, per-wave ALiBi-window gate.
// Grid (4 pairs, 64 b*h).
// ---------------------------------------------------------------------------
__global__ __launch_bounds__(512, 2) void attn8w(
    const unsigned short* __restrict__ qh, const unsigned short* __restrict__ kh,
    const unsigned short* __restrict__ vt, unsigned short* __restrict__ aout)
{
    __shared__ __align__(16) unsigned short Kl[2][128 * 64];
    __shared__ __align__(16) unsigned short Vl[2][64 * 128];

    const int j   = blockIdx.x;            // 0..3
    const int bh  = blockIdx.y;
    const int h   = bh & 15, b = bh >> 4;
    const int tid = threadIdx.x, wid = tid >> 6, lane = tid & 63;
    const int l31 = lane & 31, hi = lane >> 5;

    const int cA = 7 - j, cB = j;
    const int ntA = 2 * cA + 2;            // KVBLK=128 tiles for chunk A
    const int nt  = 18;                    // ntA + ntB (uniform)

    const unsigned short* Qb = qh + bh * (TSEQ * HDIM);
    const unsigned short* Kb = kh + bh * (TSEQ * HDIM);
    const unsigned short* Vb = vt + bh * (TSEQ * HDIM);  // [d][t]

    const float slope2 = exp2f(-0.5f * (float)(h + 1)) * LOG2E;
    const int   Wwin   = (int)ceilf(40.0f / slope2);     // ALiBi window

    // staging lane constants (source-side XOR swizzle, LDS dest linear)
    const int krow = lane >> 3;            // K: row within 8-row chunk
    const int kgc  = (lane & 7) ^ krow;    // K: swizzled 16B chunk
    const int vrow = lane >> 4;            // V: d-row within 4-row chunk
    const int vcc  = lane & 15;

#define STAGE(BUF, KV) do {                                                   \
    _Pragma("unroll")                                                         \
    for (int i_ = 0; i_ < 2; ++i_) {                                          \
        int cz_ = wid * 2 + i_;                       /* 0..15 */             \
        gload16(&Kb[((KV) + cz_ * 8 + krow) * 64 + kgc * 8],                  \
                &Kl[BUF][cz_ * 512]);                                         \
        int d_ = cz_ * 4 + vrow;                                              \
        int gc_ = vcc ^ (d_ & 15);                                            \
        gload16(&Vb[d_ * 2048 + (KV) + gc_ * 8], &Vl[BUF][cz_ * 512]);        \
    } } while (0)

    // per-chunk state (starts on chunk A)
    int qw = cA * 256 + wid * 32;          // wave's first q row
    int qg = qw + l31;                     // lane's q row
    u16x8 qf[4];                           // Q B-frags (pre-scaled by QSCALE)
    #pragma unroll
    for (int kf = 0; kf < 4; ++kf)
        qf[kf] = *(const u16x8*)&Qb[qg * 64 + kf * 16 + hi * 8];
    float m_r = -1e30f, l_r = 0.f;
    f32x16v Ot[2] = {};                    // O^T: d = dn*32+(r&3)+8*(r>>2)+4*hi

    STAGE(0, 0);                           // prologue: tile 0 (chunk A)
    int cur = 0;

    for (int t = 0; t < nt; ++t) {
        const int kv0 = (t < ntA ? t : t - ntA) * 128;
        __syncthreads();                   // drains this tile's loads

        if (t + 1 < nt) {
            const int t1 = t + 1;
            STAGE(cur ^ 1, (t1 < ntA ? t1 : t1 - ntA) * 128);
        }

        // wave-level gates: causal top + ALiBi window bottom
        if (kv0 <= qw + 31 && kv0 + 127 >= qw - Wwin) {
            const int v0 = qw - kv0;       // >= 0 (kv0 aligned to 128 <= qw)
            int nkv2 = (v0 >> 5) + 1; if (nkv2 > 4) nkv2 = 4;
            const bool diag = (kv0 + 127 > qw);

            // S^T = K . Q (raw scores; scale folded into Q)
            f32x16v st[4];
            __builtin_amdgcn_s_setprio(1);
            #pragma unroll
            for (int kv2 = 0; kv2 < 4; ++kv2) {
                if (kv2 < nkv2) {
                    f32x16v a = {};
                    #pragma unroll
                    for (int kf = 0; kf < 4; ++kf) {
                        u16x8 ka = *(const u16x8*)&Kl[cur][(kv2 * 32 + l31) * 64 +
                                                           (((kf * 2 + hi) ^ (l31 & 7)) * 8)];
                        a = mfma32(ka, qf[kf], a);
                    }
                    st[kv2] = a;
                } else {
                    st[kv2] = (f32x16v)(-1e30f);
                }
            }
            __builtin_amdgcn_s_setprio(0);

            // causal mask on raw scores (diagonal tile only)
            if (diag) {
                #pragma unroll
                for (int kv2 = 0; kv2 < 4; ++kv2) {
                    if (kv2 < nkv2) {
                        #pragma unroll
                        for (int r = 0; r < 16; ++r) {
                            int kv = kv0 + kv2 * 32 + (r & 3) + 8 * (r >> 2) + 4 * hi;
                            if (kv > qg) st[kv2][r] = -1e30f;
                        }
                    }
                }
            }

            // raw-score row max (in-lane tree + cross-half swap)
            float t16[16];
            #pragma unroll
            for (int i = 0; i < 16; ++i)
                t16[i] = fmaxf(fmaxf(st[0][i], st[1][i]), fmaxf(st[2][i], st[3][i]));
            #pragma unroll
            for (int i = 0; i < 8; ++i) t16[i] = fmaxf(t16[i], t16[i + 8]);
            #pragma unroll
            for (int i = 0; i < 4; ++i) t16[i] = fmaxf(t16[i], t16[i + 4]);
            float rm = fmaxf(fmaxf(t16[0], t16[1]), fmaxf(t16[2], t16[3]));
            rm = fmaxf(rm, __shfl_xor(rm, 32, 64));

            // upper bound on biased max: raw max + largest in-tile bias
            int kvmax = kv0 + 127; if (kvmax > qw + 31) kvmax = qw + 31;
            float cand = rm + slope2 * (float)(kvmax - 2047);

            // defer-max: rescale only when the bound moved by > 8
            if (!__all(cand - m_r <= 8.0f)) {
                float mn = fmaxf(m_r, cand);
                float alpha = exp2f(m_r - mn);
                m_r = mn;
                l_r *= alpha;
                Ot[0] *= alpha;
                Ot[1] *= alpha;
            }

            // per-kv2: exp2 (bias fused), partial sum, pack to bf16 (st dies)
            unsigned pku[4][8];
            float s16[16] = {};
            #pragma unroll
            for (int kv2 = 0; kv2 < 4; ++kv2) {
                if (kv2 < nkv2) {
                    float base2 = slope2 * (float)(kv0 + kv2 * 32 + 4 * hi - 2047) - m_r;
                    #pragma unroll
                    for (int r = 0; r < 16; ++r) {
                        float koff = (float)((r & 3) + 8 * (r >> 2));
                        st[kv2][r] = exp2f(st[kv2][r] + fmaf(slope2, koff, base2));
                        s16[r] += st[kv2][r];
                    }
                    #pragma unroll
                    for (int idx = 0; idx < 8; ++idx) {
                        unsigned lo2 = __builtin_bit_cast(unsigned short, (__bf16)st[kv2][2 * idx]);
                        unsigned hh = __builtin_bit_cast(unsigned short, (__bf16)st[kv2][2 * idx + 1]);
                        pku[kv2][idx] = lo2 | (hh << 16);
                    }
                }
            }
            #pragma unroll
            for (int i = 0; i < 8; ++i) s16[i] += s16[i + 8];
            #pragma unroll
            for (int i = 0; i < 4; ++i) s16[i] += s16[i + 4];
            float rs = (s16[0] + s16[1]) + (s16[2] + s16[3]);
            rs += __shfl_xor(rs, 32, 64);
            l_r += rs;

            // O^T += V^T . P^T (skip masked kf pairs)
            __builtin_amdgcn_s_setprio(1);
            #pragma unroll
            for (int kf = 0; kf < 8; ++kf) {
                if ((kf >> 1) < nkv2) {
                    const int kv2 = kf >> 1, base = 4 * (kf & 1);
                    unsigned s0 = hi ? pku[kv2][base + 0] : pku[kv2][base + 2];
                    unsigned s1 = hi ? pku[kv2][base + 1] : pku[kv2][base + 3];
                    unsigned r0 = __shfl_xor(s0, 32, 64);
                    unsigned r1 = __shfl_xor(s1, 32, 64);
                    u32x4 w;
                    w[0] = hi ? r0 : pku[kv2][base + 0];
                    w[1] = hi ? r1 : pku[kv2][base + 1];
                    w[2] = hi ? pku[kv2][base + 2] : r0;
                    w[3] = hi ? pku[kv2][base + 3] : r1;
                    u16x8 pb = __builtin_bit_cast(u16x8, w);
                    #pragma unroll
                    for (int dn = 0; dn < 2; ++dn) {
                        u16x8 va = *(const u16x8*)&Vl[cur][(dn * 32 + l31) * 128 +
                                                           (((kf * 2 + hi) ^ (l31 & 15)) * 8)];
                        Ot[dn] = mfma32(va, pb, Ot[dn]);
                    }
                }
            }
            __builtin_amdgcn_s_setprio(0);
        }

        // boundary: finish chunk A, switch state to chunk B
        if (t == ntA - 1) {
            float rl = 1.0f / l_r;
            #pragma unroll
            for (int dn = 0; dn < 2; ++dn)
                #pragma unroll
                for (int rq = 0; rq < 4; ++rq) {
                    u16x4 o;
                    #pragma unroll
                    for (int jj = 0; jj < 4; ++jj)
                        o[jj] = f2bf(Ot[dn][rq * 4 + jj] * rl);
                    int d = dn * 32 + 8 * rq + 4 * hi;
                    *(u16x4*)&aout[(b * 2048 + qg) * 1024 + h * 64 + d] = o;
                }
            qw = cB * 256 + wid * 32;
            qg = qw + l31;
            #pragma unroll
            for (int kf = 0; kf < 4; ++kf)
                qf[kf] = *(const u16x8*)&Qb[qg * 64 + kf * 16 + hi * 8];
            m_r = -1e30f; l_r = 0.f;
            Ot[0] = (f32x16v){};
            Ot[1] = (f32x16v){};
        }

        cur ^= 1;
    }

    // final epilogue (chunk B)
    float rl = 1.0f / l_r;
    #pragma unroll
    for (int dn = 0; dn < 2; ++dn)
        #pragma unroll
        for (int rq = 0; rq < 4; ++rq) {
            u16x4 o;
            #pragma unroll
            for (int jj = 0; jj < 4; ++jj)
                o[jj] = f2bf(Ot[dn][rq * 4 + jj] * rl);
            int d = dn * 32 + 8 * rq + 4 * hi;
            *(u16x4*)&aout[(b * 2048 + qg) * 1024 + h * 64 + d] = o;
        }
#undef STAGE
}

// ---------------------------------------------------------------------------
extern "C" void kernel_launch(void* const* d_in, const int* in_sizes, int n_in,
                              void* d_out, int out_size, void* d_ws, size_t ws_size,
                              hipStream_t stream)
{
    const float* x  = (const float*)d_in[0];
    const float* Wq = (const float*)d_in[1];
    const float* Wk = (const float*)d_in[2];
    const float* Wv = (const float*)d_in[3];
    const float* Wo = (const float*)d_in[4];

    unsigned short* ws = (unsigned short*)d_ws;
    unsigned short* wb = ws;                       // 4 x 1M bf16 (W^T: q,k,v,o)
    unsigned short* xb = ws + 4194304;             // 8M bf16
    unsigned short* qh = ws + 12582912;
    unsigned short* kh = qh + 8388608;
    unsigned short* vt = kh + 8388608;
    unsigned short* ao = xb;                       // alias: xb dead after QKV GEMM

    castx<<<dim3(8192), dim3(256), 0, stream>>>(x, xb);
    wtcast<<<dim3(16, 16, 4), dim3(256), 0, stream>>>(Wq, Wk, Wv, Wo, wb);
    gemm_gl<0><<<dim3(8, 64, 3), dim3(256), 0, stream>>>(xb, wb, qh, (float*)nullptr);
    attn8w<<<dim3(4, 64), dim3(512), 0, stream>>>(qh, kh, vt, ao);
    gemm_gl<1><<<dim3(8, 64, 1), dim3(256), 0, stream>>>(
        ao, wb + 3 * 1048576, (unsigned short*)nullptr, (float*)d_out);
}

// Round 14
// 227.402 us; speedup vs baseline: 1.7495x; 1.0067x over previous
//
#include <hip/hip_runtime.h>
#include <hip/hip_bf16.h>

// Problem constants: B=4, T=2048, C=1024, NH=16, HD=64
#define TSEQ   2048
#define CDIM   1024
#define NHEAD  16
#define HDIM   64

typedef float f32x4  __attribute__((ext_vector_type(4)));
typedef float f32x16v __attribute__((ext_vector_type(16)));
typedef __bf16 bf16x8 __attribute__((ext_vector_type(8)));
typedef unsigned short u16x8 __attribute__((ext_vector_type(8)));
typedef unsigned short u16x4 __attribute__((ext_vector_type(4)));
typedef unsigned int   u32x4 __attribute__((ext_vector_type(4)));

#define QSCALE 0.18033688011112042f   // 0.125 * log2(e)
#define LOG2E  1.4426950408889634f

static __device__ __forceinline__ unsigned short f2bf(float f) {
    unsigned u = __builtin_bit_cast(unsigned, f);
    unsigned r = u + 0x7FFFu + ((u >> 16) & 1u);   // round-to-nearest-even
    return (unsigned short)(r >> 16);
}

static __device__ __forceinline__ f32x4 mfma16(u16x8 a, u16x8 b, f32x4 c) {
    return __builtin_amdgcn_mfma_f32_16x16x32_bf16(
        __builtin_bit_cast(bf16x8, a), __builtin_bit_cast(bf16x8, b), c, 0, 0, 0);
}
static __device__ __forceinline__ f32x16v mfma32(u16x8 a, u16x8 b, f32x16v c) {
    return __builtin_amdgcn_mfma_f32_32x32x16_bf16(
        __builtin_bit_cast(bf16x8, a), __builtin_bit_cast(bf16x8, b), c, 0, 0, 0);
}

static __device__ __forceinline__ void gload16(const void* g, void* l) {
    __builtin_amdgcn_global_load_lds(
        (const __attribute__((address_space(1))) unsigned int*)g,
        (__attribute__((address_space(3))) unsigned int*)l, 16, 0, 0);
}

// Workspace layout (u16 units):
//   wb : 0        .. 4194303   (W^T q,k,v,o bf16, 1M each -- TRANSPOSED [n][k])
//   xb : 4194304  .. 12582911  (x bf16, 8M) -- reused as `ao` after QKV GEMM
//   qh : 12582912 .. 20971519  ([B,NH,T,HD] bf16, pre-scaled by QSCALE)
//   kh : 20971520 .. 29359103  ([B,NH,T,HD] bf16)
//   vt : 29359104 .. 37748735  ([B,NH,HD,T] bf16 -- V TRANSPOSED)

// ---------------------------------------------------------------------------
__global__ __launch_bounds__(256) void castx(
    const float* __restrict__ x, unsigned short* __restrict__ xb)
{
    int t = blockIdx.x * 256 + threadIdx.x;   // float4 index, < 2097152
    f32x4 v = *(const f32x4*)&x[t * 4];
    u16x4 o;
    o[0] = f2bf(v[0]); o[1] = f2bf(v[1]); o[2] = f2bf(v[2]); o[3] = f2bf(v[3]);
    *(u16x4*)&xb[t * 4] = o;
}

// ---------------------------------------------------------------------------
__global__ __launch_bounds__(256) void wtcast(
    const float* __restrict__ wq, const float* __restrict__ wk,
    const float* __restrict__ wv, const float* __restrict__ wo,
    unsigned short* __restrict__ wt)
{
    __shared__ unsigned short t[64 * 72];
    const int z = blockIdx.z;
    const float* src = (z == 0) ? wq : (z == 1) ? wk : (z == 2) ? wv : wo;
    const int k0 = blockIdx.x * 64, n0 = blockIdx.y * 64, tid = threadIdx.x;

    #pragma unroll
    for (int i = 0; i < 4; ++i) {
        int idx = i * 256 + tid;
        int r = idx >> 4, c4 = idx & 15;
        f32x4 v = *(const f32x4*)&src[(k0 + r) * 1024 + n0 + c4 * 4];
        u16x4 o;
        o[0] = f2bf(v[0]); o[1] = f2bf(v[1]); o[2] = f2bf(v[2]); o[3] = f2bf(v[3]);
        *(u16x4*)&t[r * 72 + c4 * 4] = o;
    }
    __syncthreads();
    #pragma unroll
    for (int i = 0; i < 2; ++i) {
        int idx = i * 256 + tid;
        int n = idx >> 3, k8 = idx & 7;
        u16x8 o;
        #pragma unroll
        for (int e = 0; e < 8; ++e) o[e] = t[(k8 * 8 + e) * 72 + n];
        *(u16x8*)&wt[z * 1048576 + (n0 + n) * 1024 + k0 + k8 * 8] = o;
    }
}

// ---------------------------------------------------------------------------
template<int MODE>
__global__ __launch_bounds__(256) void gemm_gl(
    const unsigned short* __restrict__ A, const unsigned short* __restrict__ WT,
    unsigned short* __restrict__ outb, float* __restrict__ outf)
{
    __shared__ __align__(16) unsigned short Al[128 * 64];
    __shared__ __align__(16) unsigned short Bl[128 * 64];

    const int tid  = threadIdx.x;
    const int z    = blockIdx.z;
    const int m0   = blockIdx.y * 128;
    const int n0   = blockIdx.x * 128;
    const unsigned short* W = WT + (MODE == 0 ? z * 1048576 : 0);

    const int wid  = tid >> 6, lane = tid & 63;
    const int wr   = (wid >> 1) * 64, wc = (wid & 1) * 64;
    const int lrow = lane & 15, lk = (lane >> 4) * 8;

    f32x4 acc[4][4] = {};

    for (int kt = 0; kt < 16; ++kt) {
        __syncthreads();
        #pragma unroll
        for (int c = 0; c < 4; ++c) {
            int cz = wid * 4 + c;
            int row = cz * 8 + (lane >> 3), col = (lane & 7) * 8;
            gload16(&A[(m0 + row) * 1024 + kt * 64 + col], &Al[cz * 512]);
            gload16(&W[(n0 + row) * 1024 + kt * 64 + col], &Bl[cz * 512]);
        }
        __syncthreads();
        #pragma unroll
        for (int ks = 0; ks < 2; ++ks) {
            u16x8 af[4], bfr[4];
            #pragma unroll
            for (int m = 0; m < 4; ++m)
                af[m] = *(const u16x8*)&Al[(wr + m * 16 + lrow) * 64 + ks * 32 + lk];
            #pragma unroll
            for (int n = 0; n < 4; ++n)
                bfr[n] = *(const u16x8*)&Bl[(wc + n * 16 + lrow) * 64 + ks * 32 + lk];
            #pragma unroll
            for (int m = 0; m < 4; ++m)
                #pragma unroll
                for (int n = 0; n < 4; ++n)
                    acc[m][n] = mfma16(af[m], bfr[n], acc[m][n]);
        }
    }

    const int g = lane >> 4;
    #pragma unroll
    for (int m = 0; m < 4; ++m)
        #pragma unroll
        for (int n = 0; n < 4; ++n)
            #pragma unroll
            for (int j = 0; j < 4; ++j) {
                int grow = m0 + wr + m * 16 + g * 4 + j;
                int gcol = n0 + wc + n * 16 + lrow;
                float val = acc[m][n][j];
                if (MODE == 0) {
                    int b = grow >> 11, t = grow & 2047;
                    int h = gcol >> 6,  d = gcol & 63;
                    if (z == 0) val *= QSCALE;
                    if (z == 2)
                        outb[z * 8388608 + (((b << 4) + h) * 64 + d) * 2048 + t] = f2bf(val);
                    else
                        outb[z * 8388608 + (((b << 4) + h) * 2048 + t) * 64 + d] = f2bf(val);
                } else {
                    outf[grow * 1024 + gcol] = val;
                }
            }
}

// ---------------------------------------------------------------------------
// Kernel 3: 8-wave single-chunk flash attention with complementary-length
// co-location. Grid (8,64) = 512 blocks = 2 x CU count; dispatch places block
// i and i+256 (same x, bh vs bh+32) on the same CU, so c = (bh<32 ? 7-x : x)
// makes each CU's two resident blocks' chains sum to <= 18 tiles while
// overlapping as INDEPENDENT chains (no shared barrier) -> 4 waves/SIMD of
// uncorrelated work. Windowed staging start shrinks h<10 chains further.
// Body = r13 verbatim: KVBLK=128 dbuf (64KB LDS), XOR-swizzled
// global_load_lds, swapped QK^T 32x32, raw-max bound, fused bias-exp2,
// defer-max, nkv2 diag skip, per-wave window gate. launch_bounds(512,2).
// ---------------------------------------------------------------------------
__global__ __launch_bounds__(512, 2) void attn8s(
    const unsigned short* __restrict__ qh, const unsigned short* __restrict__ kh,
    const unsigned short* __restrict__ vt, unsigned short* __restrict__ aout)
{
    __shared__ __align__(16) unsigned short Kl[2][128 * 64];
    __shared__ __align__(16) unsigned short Vl[2][64 * 128];

    const int bh  = blockIdx.y;
    const int h   = bh & 15, b = bh >> 4;
    const int c   = (bh < 32) ? (7 - (int)blockIdx.x) : (int)blockIdx.x;
    const int tid = threadIdx.x, wid = tid >> 6, lane = tid & 63;
    const int l31 = lane & 31, hi = lane >> 5;

    const unsigned short* Qb = qh + bh * (TSEQ * HDIM);
    const unsigned short* Kb = kh + bh * (TSEQ * HDIM);
    const unsigned short* Vb = vt + bh * (TSEQ * HDIM);  // [d][t]

    const float slope2 = exp2f(-0.5f * (float)(h + 1)) * LOG2E;
    const int   Wwin   = (int)ceilf(40.0f / slope2);     // ALiBi window

    // block tile range: windowed start .. diagonal tile of top wave
    int blo = c * 256 - Wwin;
    const int t0     = (blo > 0) ? (blo >> 7) : 0;
    const int t_last = 2 * c + 1;

    const int qw = c * 256 + wid * 32;     // wave's first q row
    const int qg = qw + l31;               // lane's q row

    // staging lane constants (source-side XOR swizzle, LDS dest linear)
    const int krow = lane >> 3;            // K: row within 8-row chunk
    const int kgc  = (lane & 7) ^ krow;    // K: swizzled 16B chunk
    const int vrow = lane >> 4;            // V: d-row within 4-row chunk
    const int vcc  = lane & 15;

#define STAGE(BUF, KV) do {                                                   \
    _Pragma("unroll")                                                         \
    for (int i_ = 0; i_ < 2; ++i_) {                                          \
        int cz_ = wid * 2 + i_;                       /* 0..15 */             \
        gload16(&Kb[((KV) + cz_ * 8 + krow) * 64 + kgc * 8],                  \
                &Kl[BUF][cz_ * 512]);                                         \
        int d_ = cz_ * 4 + vrow;                                              \
        int gc_ = vcc ^ (d_ & 15);                                            \
        gload16(&Vb[d_ * 2048 + (KV) + gc_ * 8], &Vl[BUF][cz_ * 512]);        \
    } } while (0)

    // Q B-frags: col = l31 -> q row, k = kf*16 + hi*8 + i (pre-scaled)
    u16x8 qf[4];
    #pragma unroll
    for (int kf = 0; kf < 4; ++kf)
        qf[kf] = *(const u16x8*)&Qb[qg * 64 + kf * 16 + hi * 8];
    float m_r = -1e30f, l_r = 0.f;
    f32x16v Ot[2] = {};                    // O^T: d = dn*32+(r&3)+8*(r>>2)+4*hi

    STAGE(0, t0 * 128);                    // prologue
    int cur = 0;

    for (int t = t0; t <= t_last; ++t) {
        const int kv0 = t * 128;
        __syncthreads();                   // drains this tile's loads

        if (t < t_last) STAGE(cur ^ 1, (t + 1) * 128);

        // wave-level gates: causal top + ALiBi window bottom
        if (kv0 <= qw + 31 && kv0 + 127 >= qw - Wwin) {
            const int v0 = qw - kv0;       // >= 0 (kv0 <= qw here)
            int nkv2 = (v0 >> 5) + 1; if (nkv2 > 4) nkv2 = 4;
            const bool diag = (kv0 + 127 > qw);

            // S^T = K . Q (raw scores; scale folded into Q)
            f32x16v st[4];
            __builtin_amdgcn_s_setprio(1);
            #pragma unroll
            for (int kv2 = 0; kv2 < 4; ++kv2) {
                if (kv2 < nkv2) {
                    f32x16v a = {};
                    #pragma unroll
                    for (int kf = 0; kf < 4; ++kf) {
                        u16x8 ka = *(const u16x8*)&Kl[cur][(kv2 * 32 + l31) * 64 +
                                                           (((kf * 2 + hi) ^ (l31 & 7)) * 8)];
                        a = mfma32(ka, qf[kf], a);
                    }
                    st[kv2] = a;
                } else {
                    st[kv2] = (f32x16v)(-1e30f);
                }
            }
            __builtin_amdgcn_s_setprio(0);

            // causal mask on raw scores (diagonal tile only)
            if (diag) {
                #pragma unroll
                for (int kv2 = 0; kv2 < 4; ++kv2) {
                    if (kv2 < nkv2) {
                        #pragma unroll
                        for (int r = 0; r < 16; ++r) {
                            int kv = kv0 + kv2 * 32 + (r & 3) + 8 * (r >> 2) + 4 * hi;
                            if (kv > qg) st[kv2][r] = -1e30f;
                        }
                    }
                }
            }

            // raw-score row max (in-lane tree + cross-half swap)
            float t16[16];
            #pragma unroll
            for (int i = 0; i < 16; ++i)
                t16[i] = fmaxf(fmaxf(st[0][i], st[1][i]), fmaxf(st[2][i], st[3][i]));
            #pragma unroll
            for (int i = 0; i < 8; ++i) t16[i] = fmaxf(t16[i], t16[i + 8]);
            #pragma unroll
            for (int i = 0; i < 4; ++i) t16[i] = fmaxf(t16[i], t16[i + 4]);
            float rm = fmaxf(fmaxf(t16[0], t16[1]), fmaxf(t16[2], t16[3]));
            rm = fmaxf(rm, __shfl_xor(rm, 32, 64));

            // upper bound on biased max: raw max + largest in-tile bias
            int kvmax = kv0 + 127; if (kvmax > qw + 31) kvmax = qw + 31;
            float cand = rm + slope2 * (float)(kvmax - 2047);

            // defer-max: rescale only when the bound moved by > 8
            if (!__all(cand - m_r <= 8.0f)) {
                float mn = fmaxf(m_r, cand);
                float alpha = exp2f(m_r - mn);
                m_r = mn;
                l_r *= alpha;
                Ot[0] *= alpha;
                Ot[1] *= alpha;
            }

            // per-kv2: exp2 (bias fused), partial sum, pack to bf16 (st dies)
            unsigned pku[4][8];
            float s16[16] = {};
            #pragma unroll
            for (int kv2 = 0; kv2 < 4; ++kv2) {
                if (kv2 < nkv2) {
                    float base2 = slope2 * (float)(kv0 + kv2 * 32 + 4 * hi - 2047) - m_r;
                    #pragma unroll
                    for (int r = 0; r < 16; ++r) {
                        float koff = (float)((r & 3) + 8 * (r >> 2));
                        st[kv2][r] = exp2f(st[kv2][r] + fmaf(slope2, koff, base2));
                        s16[r] += st[kv2][r];
                    }
                    #pragma unroll
                    for (int idx = 0; idx < 8; ++idx) {
                        unsigned lo2 = __builtin_bit_cast(unsigned short, (__bf16)st[kv2][2 * idx]);
                        unsigned hh = __builtin_bit_cast(unsigned short, (__bf16)st[kv2][2 * idx + 1]);
                        pku[kv2][idx] = lo2 | (hh << 16);
                    }
                }
            }
            #pragma unroll
            for (int i = 0; i < 8; ++i) s16[i] += s16[i + 8];
            #pragma unroll
            for (int i = 0; i < 4; ++i) s16[i] += s16[i + 4];
            float rs = (s16[0] + s16[1]) + (s16[2] + s16[3]);
            rs += __shfl_xor(rs, 32, 64);
            l_r += rs;

            // O^T += V^T . P^T (skip masked kf pairs)
            __builtin_amdgcn_s_setprio(1);
            #pragma unroll
            for (int kf = 0; kf < 8; ++kf) {
                if ((kf >> 1) < nkv2) {
                    const int kv2 = kf >> 1, base = 4 * (kf & 1);
                    unsigned s0 = hi ? pku[kv2][base + 0] : pku[kv2][base + 2];
                    unsigned s1 = hi ? pku[kv2][base + 1] : pku[kv2][base + 3];
                    unsigned r0 = __shfl_xor(s0, 32, 64);
                    unsigned r1 = __shfl_xor(s1, 32, 64);
                    u32x4 w;
                    w[0] = hi ? r0 : pku[kv2][base + 0];
                    w[1] = hi ? r1 : pku[kv2][base + 1];
                    w[2] = hi ? pku[kv2][base + 2] : r0;
                    w[3] = hi ? pku[kv2][base + 3] : r1;
                    u16x8 pb = __builtin_bit_cast(u16x8, w);
                    #pragma unroll
                    for (int dn = 0; dn < 2; ++dn) {
                        u16x8 va = *(const u16x8*)&Vl[cur][(dn * 32 + l31) * 128 +
                                                           (((kf * 2 + hi) ^ (l31 & 15)) * 8)];
                        Ot[dn] = mfma32(va, pb, Ot[dn]);
                    }
                }
            }
            __builtin_amdgcn_s_setprio(0);
        }

        cur ^= 1;
    }

    // epilogue: normalize, write bf16 [B*T][C]; r-quads give contiguous d
    float rl = 1.0f / l_r;
    #pragma unroll
    for (int dn = 0; dn < 2; ++dn)
        #pragma unroll
        for (int rq = 0; rq < 4; ++rq) {
            u16x4 o;
            #pragma unroll
            for (int jj = 0; jj < 4; ++jj)
                o[jj] = f2bf(Ot[dn][rq * 4 + jj] * rl);
            int d = dn * 32 + 8 * rq + 4 * hi;
            *(u16x4*)&aout[(b * 2048 + qg) * 1024 + h * 64 + d] = o;
        }
#undef STAGE
}

// ---------------------------------------------------------------------------
extern "C" void kernel_launch(void* const* d_in, const int* in_sizes, int n_in,
                              void* d_out, int out_size, void* d_ws, size_t ws_size,
                              hipStream_t stream)
{
    const float* x  = (const float*)d_in[0];
    const float* Wq = (const float*)d_in[1];
    const float* Wk = (const float*)d_in[2];
    const float* Wv = (const float*)d_in[3];
    const float* Wo = (const float*)d_in[4];

    unsigned short* ws = (unsigned short*)d_ws;
    unsigned short* wb = ws;                       // 4 x 1M bf16 (W^T: q,k,v,o)
    unsigned short* xb = ws + 4194304;             // 8M bf16
    unsigned short* qh = ws + 12582912;
    unsigned short* kh = qh + 8388608;
    unsigned short* vt = kh + 8388608;
    unsigned short* ao = xb;                       // alias: xb dead after QKV GEMM

    castx<<<dim3(8192), dim3(256), 0, stream>>>(x, xb);
    wtcast<<<dim3(16, 16, 4), dim3(256), 0, stream>>>(Wq, Wk, Wv, Wo, wb);
    gemm_gl<0><<<dim3(8, 64, 3), dim3(256), 0, stream>>>(xb, wb, qh, (float*)nullptr);
    attn8s<<<dim3(8, 64), dim3(512), 0, stream>>>(qh, kh, vt, ao);
    gemm_gl<1><<<dim3(8, 64, 1), dim3(256), 0, stream>>>(
        ao, wb + 3 * 1048576, (unsigned short*)nullptr, (float*)d_out);
}